// Round 21
// baseline (43.576 us; speedup 1.0000x reference)
//
#include <hip/hip_runtime.h>
#include <hip/hip_bf16.h>
#include <cstdint>

// Problem constants (N read from in_sizes at launch; C, D fixed by reference).
#define DIM 64
#define NC  1024

typedef __attribute__((ext_vector_type(8))) __bf16 bf16x8;
typedef __attribute__((ext_vector_type(8))) short short8;
typedef __attribute__((ext_vector_type(4))) float f32x4;

static __device__ __forceinline__ unsigned short f32_to_bf16_rne(float f) {
    unsigned int u = __builtin_bit_cast(unsigned int, f);
    unsigned int r = u + 0x7FFFu + ((u >> 16) & 1u);
    return (unsigned short)(r >> 16);
}

// ---------------------------------------------------------------------------
// Fused prep (ONE launch, 17 blocks x 64 threads) — r20-proven.
//   block 0: normalized |coefs| weights -> wc2[c].x (wave shfl-reduce).
//   blocks 1..16: center norms -> wc2[c].y (plain f32); bf16(-2*centers)
//            in MFMA B-fragment layout -> bfrag.
// B-fragment layout for mfma_f32_16x16x32_bf16:
//   lane supplies B[k][col] with col = lane&15, k = (lane>>4)*8 + j.
//   Stored as bfrag[(tile*2 + kb)*64 + lane] : short8 (16B per lane).
// ---------------------------------------------------------------------------
__global__ __launch_bounds__(64) void prep_kernel(
    const float* __restrict__ coefs,
    const float* __restrict__ centers,
    float2* __restrict__ wc2,
    short8* __restrict__ bfrag)
{
    const int tid = threadIdx.x;

    if (blockIdx.x == 0) {
        float a[16];
        float s = 0.0f;
#pragma unroll
        for (int q = 0; q < 4; ++q) {
            f32x4 v = *(const f32x4*)(coefs + tid * 16 + q * 4);
#pragma unroll
            for (int j = 0; j < 4; ++j) {
                a[q * 4 + j] = fabsf(v[j]);
                s += a[q * 4 + j];
            }
        }
        s += __shfl_xor(s, 1, 64);
        s += __shfl_xor(s, 2, 64);
        s += __shfl_xor(s, 4, 64);
        s += __shfl_xor(s, 8, 64);
        s += __shfl_xor(s, 16, 64);
        s += __shfl_xor(s, 32, 64);
        const float inv = (s == 0.0f) ? 1.0f : (1.0f / s);
#pragma unroll
        for (int j = 0; j < 16; ++j)
            wc2[tid * 16 + j].x = a[j] * inv;
        return;
    }

    const int c = (blockIdx.x - 1) * 64 + tid;
    const float4* row = (const float4*)(centers + (size_t)c * DIM);

    float vals[DIM];
    float c2 = 0.0f;
#pragma unroll
    for (int q = 0; q < DIM / 4; ++q) {
        float4 v = row[q];
        vals[q * 4 + 0] = v.x; vals[q * 4 + 1] = v.y;
        vals[q * 4 + 2] = v.z; vals[q * 4 + 3] = v.w;
        c2 = fmaf(v.x, v.x, c2); c2 = fmaf(v.y, v.y, c2);
        c2 = fmaf(v.z, v.z, c2); c2 = fmaf(v.w, v.w, c2);
    }
    wc2[c].y = c2;

    const int tile = c >> 4;
    const int colL = c & 15;
#pragma unroll
    for (int kb = 0; kb < 2; ++kb) {
#pragma unroll
        for (int h = 0; h < 4; ++h) {
            short8 p;
#pragma unroll
            for (int j = 0; j < 8; ++j) {
                float v = -2.0f * vals[kb * 32 + h * 8 + j];
                p[j] = (short)f32_to_bf16_rne(v);
            }
            bfrag[(tile * 2 + kb) * 64 + (h * 16 + colL)] = p;
        }
    }
}

// ---------------------------------------------------------------------------
// Main (round 21): LDS-RESIDENT B, no in-loop staging, no in-loop barriers.
// Mechanism: hipcc refuses to pipeline GLOBAL loads in registers (sinks
// r4-15, spills r16, asm breaks r17/18, pin re-sunk r19 — the measured
// +19us stall, r14 probe). But it DOES fine-schedule LDS reads (emits
// partial lgkmcnt(N) between ds_read and MFMA — m97 evidence). So move B
// to LDS once per phase and let the in-loop path be pure lgkm.
//   block = 4 waves x 64 rows = 256 rows; each wave covers ALL 1024
//   centers -> no cross-wave combine (epilogue = wave shfl + direct store).
//   LDS: 32 tiles (64KB) + wcl (8KB) = 72KB -> 2 blocks/CU.
//   Two phases p=0,1: {barrier; bulk-fill tiles p*32..+31; barrier;
//   16 iterations of the r13 2-tile-interleave compute body (ds_read)}.
// Unlike r15: zero staging registers (VGPR stays ~r13's 64-80), one
// barrier pair per 32 tiles instead of per 4 (no lockstep convoy).
// Keep: launch_bounds(256,4), loops pinned rolled (r6 spill), VALU
// acc-init, NT x-loads.
// ---------------------------------------------------------------------------
__global__ __launch_bounds__(256, 4) void dist_kernel(
    const float* __restrict__ x,
    const float2* __restrict__ wc2,
    const char* __restrict__ bfragB,   // byte view of bfrag
    const float* __restrict__ madp,
    float* __restrict__ out)
{
    const int tid  = threadIdx.x;
    const int lane = tid & 63;
    const int wave = tid >> 6;
    const int lo = lane & 15;
    const int hi = lane >> 4;
    const int rowBase = blockIdx.x * 256 + wave * 64;

    __shared__ __align__(16) char lbuf[65536];   // 32 tiles x 2KB
    __shared__ float2 wcl[NC];                   // 8KB (w, c2) per center

    // wcl fill (once; published by the phase-0 fill barrier).
    {
        const f32x4* wsrc = (const f32x4*)wc2;
        f32x4* wdst = (f32x4*)wcl;
        wdst[tid * 2]     = wsrc[tid * 2];
        wdst[tid * 2 + 1] = wsrc[tid * 2 + 1];
    }

    // Prologue: load A rows (NT — single-use stream), bf16 fragments, x2.
    bf16x8 afrag[4][2];
    float x2v[4][4];
#pragma unroll
    for (int g = 0; g < 4; ++g) {
        const int row = rowBase + g * 16 + lo;
        const float* rp = x + (size_t)row * DIM + hi * 8;
        float s2 = 0.0f;
#pragma unroll
        for (int kb = 0; kb < 2; ++kb) {
            f32x4 v0 = __builtin_nontemporal_load((const f32x4*)(rp + kb * 32));
            f32x4 v1 = __builtin_nontemporal_load((const f32x4*)(rp + kb * 32 + 4));
            float vv[8] = {v0.x, v0.y, v0.z, v0.w, v1.x, v1.y, v1.z, v1.w};
            short8 p;
#pragma unroll
            for (int j = 0; j < 8; ++j) {
                s2 = fmaf(vv[j], vv[j], s2);
                p[j] = (short)f32_to_bf16_rne(vv[j]);
            }
            afrag[g][kb] = __builtin_bit_cast(bf16x8, p);
        }
        // lane holds 16 of row's 64 values; combine the 4 hi-groups.
        s2 += __shfl_xor(s2, 16, 64);
        s2 += __shfl_xor(s2, 32, 64);
        // Redistribute to accumulator layout (acc elem b <-> row g*16+hi*4+b).
#pragma unroll
        for (int b = 0; b < 4; ++b)
            x2v[g][b] = __shfl(s2, hi * 4 + b, 64);
    }

    float sum[4][4];
#pragma unroll
    for (int g = 0; g < 4; ++g)
#pragma unroll
        for (int b = 0; b < 4; ++b) sum[g][b] = 0.0f;

    const char* lpB = lbuf + lane * 16;   // lane-fixed LDS base

#pragma unroll 1
    for (int p = 0; p < 2; ++p) {
        // All waves done reading the previous phase's LDS (no-op cost at p=0).
        __syncthreads();
        // Bulk-fill this phase's 32 tiles (64KB): thread t copies 16 x 16B.
        {
            const char* src = bfragB + (size_t)p * 65536 + tid * 16;
            char* dst = lbuf + tid * 16;
#pragma unroll
            for (int k = 0; k < 16; ++k)
                *(f32x4*)(dst + k * 4096) = *(const f32x4*)(src + k * 4096);
        }
        __syncthreads();

#pragma unroll 1   // MUST stay rolled (round 6: full unroll -> spill)
        for (int i = 0; i < 32; i += 2) {
            // Both tiles' operands from LDS (lgkm path — compiler
            // fine-schedules partial lgkmcnt before each MFMA).
            const float2 wcA = wcl[p * 512 + i * 16 + lo];
            const float2 wcB = wcl[p * 512 + (i + 1) * 16 + lo];
            const bf16x8 a00 = *(const bf16x8*)(lpB + i * 2048);
            const bf16x8 a01 = *(const bf16x8*)(lpB + i * 2048 + 1024);
            const bf16x8 a10 = *(const bf16x8*)(lpB + i * 2048 + 2048);
            const bf16x8 a11 = *(const bf16x8*)(lpB + i * 2048 + 3072);

            // acc init on VALU (independent of matrix pipe).
            f32x4 acc0[4], acc1[4];
#pragma unroll
            for (int g = 0; g < 4; ++g)
#pragma unroll
                for (int b = 0; b < 4; ++b) {
                    acc0[g][b] = x2v[g][b] + wcA.y;
                    acc1[g][b] = x2v[g][b] + wcB.y;
                }

            // 8 independent 2-deep MFMA chains, interleaved across 2 tiles.
#pragma unroll
            for (int g = 0; g < 4; ++g)
                acc0[g] = __builtin_amdgcn_mfma_f32_16x16x32_bf16(afrag[g][0], a00, acc0[g], 0, 0, 0);
#pragma unroll
            for (int g = 0; g < 4; ++g)
                acc1[g] = __builtin_amdgcn_mfma_f32_16x16x32_bf16(afrag[g][0], a10, acc1[g], 0, 0, 0);
#pragma unroll
            for (int g = 0; g < 4; ++g)
                acc0[g] = __builtin_amdgcn_mfma_f32_16x16x32_bf16(afrag[g][1], a01, acc0[g], 0, 0, 0);
#pragma unroll
            for (int g = 0; g < 4; ++g)
                acc1[g] = __builtin_amdgcn_mfma_f32_16x16x32_bf16(afrag[g][1], a11, acc1[g], 0, 0, 0);

            // Epilogues (trans+VALU pipes; overlap the other tile's MFMAs).
#pragma unroll
            for (int g = 0; g < 4; ++g)
#pragma unroll
                for (int b = 0; b < 4; ++b) {
                    float d = __builtin_amdgcn_sqrtf(fabsf(acc0[g][b]));
                    sum[g][b] = fmaf(wcA.x, d, sum[g][b]);
                }
#pragma unroll
            for (int g = 0; g < 4; ++g)
#pragma unroll
                for (int b = 0; b < 4; ++b) {
                    float d = __builtin_amdgcn_sqrtf(fabsf(acc1[g][b]));
                    sum[g][b] = fmaf(wcB.x, d, sum[g][b]);
                }
        }
    }

    // Epilogue: wave covered ALL centers — reduce over the 16 col-lanes
    // and store directly (no LDS combine, no cross-wave traffic).
    const float mad = madp[0];
#pragma unroll
    for (int g = 0; g < 4; ++g) {
#pragma unroll
        for (int b = 0; b < 4; ++b) {
            float v = sum[g][b];
            v += __shfl_xor(v, 1, 64);
            v += __shfl_xor(v, 2, 64);
            v += __shfl_xor(v, 4, 64);
            v += __shfl_xor(v, 8, 64);
            if (lo == 0)
                __builtin_nontemporal_store(mad - v,
                    &out[rowBase + g * 16 + hi * 4 + b]);
        }
    }
}

extern "C" void kernel_launch(void* const* d_in, const int* in_sizes, int n_in,
                              void* d_out, int out_size, void* d_ws, size_t ws_size,
                              hipStream_t stream) {
    const float* x       = (const float*)d_in[0];
    const float* centers = (const float*)d_in[1];
    const float* coefs   = (const float*)d_in[2];
    const float* mad     = (const float*)d_in[3];
    float* out = (float*)d_out;

    float2* wc2   = (float2*)d_ws;
    short8* bfrag = (short8*)((char*)d_ws + NC * sizeof(float2));

    const int N = in_sizes[0] / DIM;

    prep_kernel<<<1 + NC / 64, 64, 0, stream>>>(coefs, centers, wc2, bfrag);
    dist_kernel<<<N / 256, 256, 0, stream>>>(x, wc2, (const char*)bfrag, mad, out);
}

// Round 22
// 42.999 us; speedup vs baseline: 1.0134x; 1.0134x over previous
//
#include <hip/hip_runtime.h>
#include <hip/hip_bf16.h>
#include <cstdint>

// Problem constants (N read from in_sizes at launch; C, D fixed by reference).
#define DIM 64
#define NC  1024

typedef __attribute__((ext_vector_type(8))) __bf16 bf16x8;
typedef __attribute__((ext_vector_type(8))) short short8;
typedef __attribute__((ext_vector_type(4))) float f32x4;

static __device__ __forceinline__ unsigned short f32_to_bf16_rne(float f) {
    unsigned int u = __builtin_bit_cast(unsigned int, f);
    unsigned int r = u + 0x7FFFu + ((u >> 16) & 1u);
    return (unsigned short)(r >> 16);
}

// ---------------------------------------------------------------------------
// Fused prep (ONE launch, 17 blocks x 64 threads) — r20-proven.
//   block 0: normalized |coefs| weights -> wc2[c].x (wave shfl-reduce).
//   blocks 1..16: center norms -> wc2[c].y (plain f32); bf16(-2*centers)
//            in MFMA B-fragment layout -> bfrag.
// B-fragment layout for mfma_f32_16x16x32_bf16:
//   lane supplies B[k][col] with col = lane&15, k = (lane>>4)*8 + j.
//   Stored as bfrag[(tile*2 + kb)*64 + lane] : short8 (16B per lane).
// ---------------------------------------------------------------------------
__global__ __launch_bounds__(64) void prep_kernel(
    const float* __restrict__ coefs,
    const float* __restrict__ centers,
    float2* __restrict__ wc2,
    short8* __restrict__ bfrag)
{
    const int tid = threadIdx.x;

    if (blockIdx.x == 0) {
        float a[16];
        float s = 0.0f;
#pragma unroll
        for (int q = 0; q < 4; ++q) {
            f32x4 v = *(const f32x4*)(coefs + tid * 16 + q * 4);
#pragma unroll
            for (int j = 0; j < 4; ++j) {
                a[q * 4 + j] = fabsf(v[j]);
                s += a[q * 4 + j];
            }
        }
        s += __shfl_xor(s, 1, 64);
        s += __shfl_xor(s, 2, 64);
        s += __shfl_xor(s, 4, 64);
        s += __shfl_xor(s, 8, 64);
        s += __shfl_xor(s, 16, 64);
        s += __shfl_xor(s, 32, 64);
        const float inv = (s == 0.0f) ? 1.0f : (1.0f / s);
#pragma unroll
        for (int j = 0; j < 16; ++j)
            wc2[tid * 16 + j].x = a[j] * inv;
        return;
    }

    const int c = (blockIdx.x - 1) * 64 + tid;
    const float4* row = (const float4*)(centers + (size_t)c * DIM);

    float vals[DIM];
    float c2 = 0.0f;
#pragma unroll
    for (int q = 0; q < DIM / 4; ++q) {
        float4 v = row[q];
        vals[q * 4 + 0] = v.x; vals[q * 4 + 1] = v.y;
        vals[q * 4 + 2] = v.z; vals[q * 4 + 3] = v.w;
        c2 = fmaf(v.x, v.x, c2); c2 = fmaf(v.y, v.y, c2);
        c2 = fmaf(v.z, v.z, c2); c2 = fmaf(v.w, v.w, c2);
    }
    wc2[c].y = c2;

    const int tile = c >> 4;
    const int colL = c & 15;
#pragma unroll
    for (int kb = 0; kb < 2; ++kb) {
#pragma unroll
        for (int h = 0; h < 4; ++h) {
            short8 p;
#pragma unroll
            for (int j = 0; j < 8; ++j) {
                float v = -2.0f * vals[kb * 32 + h * 8 + j];
                p[j] = (short)f32_to_bf16_rne(v);
            }
            bfrag[(tile * 2 + kb) * 64 + (h * 16 + colL)] = p;
        }
    }
}

// ---------------------------------------------------------------------------
// Main — FINAL (r13/r20 configuration; best measured total 43.3 us).
// SETTLED ANALYSIS (21 rounds):
//   - compute floor: 22.6us measured (r14 load-free probe) at 94% combined
//     issue utilization (VALU 61% + MFMA 33%) at the ~4 waves/SIMD residency
//     cap (hidden accumulator alloc — occupancy invariant to VGPR 44-64 and
//     grid 1024-4096; r4/r7/r9);
//   - the remaining ~19us is operand-fetch serialization that hipcc refuses
//     to pipeline at source level: prefetch slots sunk (r4-15), spilled
//     under sched_barrier (r16), raw-asm loads broke on backedge phis
//     (r17/18 NaN), placement pin legally re-sunk (r19), per-chunk LDS
//     staging lockstep (r15), LDS-resident B flat (r21 — lgkm path
//     serializes identically). Breaking it requires hand-scheduled asm
//     (the toolchain wall the guide documents for m97-class kernels).
// Structure: block = 256 threads = 4 waves = 2 wave-pairs.
//   Wave pair p owns rows [blockBase + p*64, +64); wave parity owns a
//   512-center half (32 tiles of 16).
//   Per tile: VALU acc-init (x2+c2), 2 MFMA (A*(-2C)) -> d^2,
//   epilogue d = sqrt(|d2|) (abs = free modifier), sum += w*d.
//   2-tile interleave for MFMA/epilogue overlap; bf16 cross-term only
//   (x2/c2/accum f32): absmax 0.0625 vs 0.256 threshold, 15 rounds stable.
// Keep: launch_bounds(256,4), outer loop pinned rolled (r6 spill lesson),
// NT x-loads/out-store.
// ---------------------------------------------------------------------------
__global__ __launch_bounds__(256, 4) void dist_kernel(
    const float* __restrict__ x,
    const float2* __restrict__ wc2,
    const bf16x8* __restrict__ bfrag,
    const float* __restrict__ madp,
    float* __restrict__ out)
{
    const int lane = threadIdx.x & 63;
    const int wave = threadIdx.x >> 6;
    const int lo = lane & 15;
    const int hi = lane >> 4;
    const int pairIdx = wave >> 1;     // which 64-row group of the block
    const int halfC  = wave & 1;       // which 512-center half
    const int rowBase = blockIdx.x * 128 + pairIdx * 64;

    __shared__ float part[4][64];

    bf16x8 afrag[4][2];
    float x2v[4][4];

    // Prologue: load A rows (NT — single-use stream), bf16 fragments, x2.
#pragma unroll
    for (int g = 0; g < 4; ++g) {
        const int row = rowBase + g * 16 + lo;
        const float* rp = x + (size_t)row * DIM + hi * 8;
        float s2 = 0.0f;
#pragma unroll
        for (int kb = 0; kb < 2; ++kb) {
            f32x4 v0 = __builtin_nontemporal_load((const f32x4*)(rp + kb * 32));
            f32x4 v1 = __builtin_nontemporal_load((const f32x4*)(rp + kb * 32 + 4));
            float vv[8] = {v0.x, v0.y, v0.z, v0.w, v1.x, v1.y, v1.z, v1.w};
            short8 p;
#pragma unroll
            for (int j = 0; j < 8; ++j) {
                s2 = fmaf(vv[j], vv[j], s2);
                p[j] = (short)f32_to_bf16_rne(vv[j]);
            }
            afrag[g][kb] = __builtin_bit_cast(bf16x8, p);
        }
        // lane holds 16 of row's 64 values; combine the 4 hi-groups.
        s2 += __shfl_xor(s2, 16, 64);
        s2 += __shfl_xor(s2, 32, 64);
        // Redistribute to accumulator layout (acc elem b <-> row g*16+hi*4+b).
#pragma unroll
        for (int b = 0; b < 4; ++b)
            x2v[g][b] = __shfl(s2, hi * 4 + b, 64);
    }

    float sum[4][4];
#pragma unroll
    for (int g = 0; g < 4; ++g)
#pragma unroll
        for (int b = 0; b < 4; ++b) sum[g][b] = 0.0f;

    const int tbase = halfC * 32;
    const bf16x8* bp = bfrag + lane;     // lane-fixed base
    const float2* wp = wc2 + lo;

    // Fill the 2-slot pipeline: slot s = tile tbase+s.
    bf16x8 pb0[2], pb1[2];
    float2 pwc[2];
#pragma unroll
    for (int s = 0; s < 2; ++s) {
        const int t = tbase + s;
        pb0[s] = bp[t * 128];
        pb1[s] = bp[t * 128 + 64];
        pwc[s] = wp[t * 16];
    }

#pragma unroll 1   // MUST stay rolled (round 6: full unroll -> spill)
    for (int i = 0; i < 32; i += 2) {
        // Capture both tiles' operands.
        const float2 wcA = pwc[0], wcB = pwc[1];
        const bf16x8 a00 = pb0[0], a01 = pb1[0];
        const bf16x8 a10 = pb0[1], a11 = pb1[1];

        // Prefetch tiles i+2, i+3 into the slots (wrap at tail; harmless).
        {
            const int n0 = i + 2, n1 = i + 3;
            const int t0 = tbase + ((n0 < 32) ? n0 : 0);
            const int t1 = tbase + ((n1 < 32) ? n1 : 0);
            pb0[0] = bp[t0 * 128]; pb1[0] = bp[t0 * 128 + 64]; pwc[0] = wp[t0 * 16];
            pb0[1] = bp[t1 * 128]; pb1[1] = bp[t1 * 128 + 64]; pwc[1] = wp[t1 * 16];
        }

        // acc init on VALU (independent of matrix pipe, schedulable early).
        f32x4 acc0[4], acc1[4];
#pragma unroll
        for (int g = 0; g < 4; ++g)
#pragma unroll
            for (int b = 0; b < 4; ++b) {
                acc0[g][b] = x2v[g][b] + wcA.y;
                acc1[g][b] = x2v[g][b] + wcB.y;
            }

        // 8 independent 2-deep MFMA chains, interleaved across the 2 tiles.
#pragma unroll
        for (int g = 0; g < 4; ++g)
            acc0[g] = __builtin_amdgcn_mfma_f32_16x16x32_bf16(afrag[g][0], a00, acc0[g], 0, 0, 0);
#pragma unroll
        for (int g = 0; g < 4; ++g)
            acc1[g] = __builtin_amdgcn_mfma_f32_16x16x32_bf16(afrag[g][0], a10, acc1[g], 0, 0, 0);
#pragma unroll
        for (int g = 0; g < 4; ++g)
            acc0[g] = __builtin_amdgcn_mfma_f32_16x16x32_bf16(afrag[g][1], a01, acc0[g], 0, 0, 0);
#pragma unroll
        for (int g = 0; g < 4; ++g)
            acc1[g] = __builtin_amdgcn_mfma_f32_16x16x32_bf16(afrag[g][1], a11, acc1[g], 0, 0, 0);

        // Epilogues (trans+VALU pipes; overlap the other tile's MFMAs).
#pragma unroll
        for (int g = 0; g < 4; ++g)
#pragma unroll
            for (int b = 0; b < 4; ++b) {
                float d = __builtin_amdgcn_sqrtf(fabsf(acc0[g][b]));
                sum[g][b] = fmaf(wcA.x, d, sum[g][b]);
            }
#pragma unroll
        for (int g = 0; g < 4; ++g)
#pragma unroll
            for (int b = 0; b < 4; ++b) {
                float d = __builtin_amdgcn_sqrtf(fabsf(acc1[g][b]));
                sum[g][b] = fmaf(wcB.x, d, sum[g][b]);
            }
    }

    // Reduce over the 16 col-lanes of this wave's half, park in LDS.
#pragma unroll
    for (int g = 0; g < 4; ++g) {
#pragma unroll
        for (int b = 0; b < 4; ++b) {
            float v = sum[g][b];
            v += __shfl_xor(v, 1, 64);
            v += __shfl_xor(v, 2, 64);
            v += __shfl_xor(v, 4, 64);
            v += __shfl_xor(v, 8, 64);
            if (lo == 0) part[wave][g * 16 + hi * 4 + b] = v;
        }
    }
    __syncthreads();

    // Combine the two center-halves and write 128 rows (NT store —
    // out is write-once, never re-read).
    const int tid = threadIdx.x;
    if (tid < 128) {
        const int p = tid >> 6;
        const int r = tid & 63;
        const float s = part[2 * p][r] + part[2 * p + 1][r];
        __builtin_nontemporal_store(madp[0] - s, &out[blockIdx.x * 128 + p * 64 + r]);
    }
}

extern "C" void kernel_launch(void* const* d_in, const int* in_sizes, int n_in,
                              void* d_out, int out_size, void* d_ws, size_t ws_size,
                              hipStream_t stream) {
    const float* x       = (const float*)d_in[0];
    const float* centers = (const float*)d_in[1];
    const float* coefs   = (const float*)d_in[2];
    const float* mad     = (const float*)d_in[3];
    float* out = (float*)d_out;

    float2* wc2   = (float2*)d_ws;
    short8* bfrag = (short8*)((char*)d_ws + NC * sizeof(float2));

    const int N = in_sizes[0] / DIM;

    prep_kernel<<<1 + NC / 64, 64, 0, stream>>>(coefs, centers, wc2, bfrag);
    dist_kernel<<<N / 128, 256, 0, stream>>>(x, wc2, (const bf16x8*)bfrag, mad, out);
}